// Round 5
// baseline (196.500 us; speedup 1.0000x reference)
//
#include <hip/hip_runtime.h>

#define BB 4
#define NN 256
#define DD 256
#define HH 256
#define NEGV -1.0e9f

typedef _Float16 half8 __attribute__((ext_vector_type(8)));
typedef __fp16   fp16x2 __attribute__((ext_vector_type(2)));
typedef float floatx4 __attribute__((ext_vector_type(4)));

// ---------------- prep: 4 rows/block, serial-K, no memset, no atomics ----------
// R24: 256 blocks x 256 thr; thread (r2 = t>>7, hp = t&127) handles rows
// row0+2*r2..+1 at h = 2*hp (float2 W1 loads shared across its 2 rows).
// W1 L2 traffic halves vs split-4 (134 MB); deterministic direct stores.
// Wst conversion: block g converts d = g (grid 256 = all d).
__global__ __launch_bounds__(256) void prep(const float* __restrict__ X,
                                            const float* __restrict__ W1,
                                            float* __restrict__ S,
                                            float* __restrict__ T,
                                            _Float16* __restrict__ Wst) {
  const int g = blockIdx.x;    // 0..255
  const int t = threadIdx.x;   // 0..255

  {  // weight conversion for d = g (R13 map)
    const float wcv = W1[(size_t)(2 * DD + g) * HH + t];
    const float wdv = W1[(size_t)(3 * DD + g) * HH + t];
    const int ks = g >> 4;
    const int dd = g & 15;
    const int q  = dd >> 2;
    const int e  = (dd & 3) * 2;
    const int hgrp = t >> 4;
    const int ccw  = t & 15;
    _Float16* p = Wst + ((size_t)((ks * 16 + hgrp) * 4 + q) * 16 + ccw) * 8 + e;
    p[0] = (_Float16)wcv;
    p[1] = (_Float16)wdv;
  }

  const int row0 = g * 4;
  __shared__ float xr[4][256];
  {
    const float2* src2 = (const float2*)(X + (size_t)row0 * DD);
    float2* xr2 = (float2*)xr;
    xr2[t]       = src2[t];
    xr2[t + 256] = src2[t + 256];
  }
  __syncthreads();

  const int r2 = t >> 7;       // row-pair 0..1
  const int h  = (t & 127) * 2;
  const float* __restrict__ xA = xr[r2 * 2];
  const float* __restrict__ xB = xr[r2 * 2 + 1];
  float saAx = 0.f, saAy = 0.f, sbAx = 0.f, sbAy = 0.f;
  float saBx = 0.f, saBy = 0.f, sbBx = 0.f, sbBy = 0.f;
#pragma unroll 16
  for (int d = 0; d < 256; ++d) {
    const float2 wa = *(const float2*)&W1[(size_t)d * HH + h];
    const float2 wb = *(const float2*)&W1[(size_t)(DD + d) * HH + h];
    const float a = xA[d], c = xB[d];
    saAx = fmaf(a, wa.x, saAx); saAy = fmaf(a, wa.y, saAy);
    sbAx = fmaf(a, wb.x, sbAx); sbAy = fmaf(a, wb.y, sbAy);
    saBx = fmaf(c, wa.x, saBx); saBy = fmaf(c, wa.y, saBy);
    sbBx = fmaf(c, wb.x, sbBx); sbBy = fmaf(c, wb.y, sbBy);
  }
  const int rA = row0 + r2 * 2, rB = rA + 1;
  *(float2*)&S[(size_t)rA * HH + h] = make_float2(saAx, saAy);
  *(float2*)&S[(size_t)rB * HH + h] = make_float2(saBx, saBy);
  *(float2*)&T[(size_t)rA * HH + h] = make_float2(sbAx, sbAy);
  *(float2*)&T[(size_t)rB * HH + h] = make_float2(sbBx, sbBy);
}

__device__ __forceinline__ half8 make_afrag(const float4 xi, const float4 xj) {
  fp16x2 p0 = __builtin_amdgcn_cvt_pkrtz(__builtin_fabsf(xi.x - xj.x), xi.x * xj.x);
  fp16x2 p1 = __builtin_amdgcn_cvt_pkrtz(__builtin_fabsf(xi.y - xj.y), xi.y * xj.y);
  fp16x2 p2 = __builtin_amdgcn_cvt_pkrtz(__builtin_fabsf(xi.z - xj.z), xi.z * xj.z);
  fp16x2 p3 = __builtin_amdgcn_cvt_pkrtz(__builtin_fabsf(xi.w - xj.w), xi.w * xj.w);
  uint4 u;
  u.x = __builtin_bit_cast(unsigned int, p0);
  u.y = __builtin_bit_cast(unsigned int, p1);
  u.z = __builtin_bit_cast(unsigned int, p2);
  u.w = __builtin_bit_cast(unsigned int, p3);
  return __builtin_bit_cast(half8, u);
}

#define MFMA16(af, bf, acc) acc = __builtin_amdgcn_mfma_f32_16x16x32_f16(af, bf, acc, 0, 0, 0)

// ---------------- score: 2 i-rows per block (R24) ------------------------------
// R22/R23 killed TLP/barrier/MLP theories (score pinned 100-107us across 4
// structures). Remaining invariant: work decomposition. R24 merges row-pairs
// (2m, 2m+1) -> per block, Wst B-frags + epilogue T/S rows + xj staging loads
// all SHARED across 2 i's: Wst L2 traffic 655->328 MB, epi loads 230->115 MB,
// K-loop 16 MFMA per 2 B-loads (2x intensity). Regs ~160 -> (512,2), no spill
// expected. Falsifier: WRITE_SIZE > 10 MB = spill; score >=95us = theory dead.
__global__ __launch_bounds__(512, 2) void score_mfma(
    const float* __restrict__ X,  const float* __restrict__ b1,
    const float* __restrict__ W2, const float* __restrict__ b2,
    const float* __restrict__ S,  const float* __restrict__ T,
    const _Float16* __restrict__ Wst, float* __restrict__ Sc) {

  const int beta = blockIdx.x;      // 0..319
  const int b    = blockIdx.y;
  int m, qt;
  if (beta < 128)      { m = beta >> 2;                    qt = beta & 3; }
  else if (beta < 224) { const int g = beta - 128; const int d3 = g / 3;
                         m = 32 + d3;                      qt = 1 + (g - 3 * d3); }
  else if (beta < 288) { const int g = beta - 224;
                         m = 64 + (g >> 1);                qt = 2 + (g & 1); }
  else                 { m = 96 + (beta - 288);            qt = 3; }
  const int i0    = m * 2;          // rows i0, i0+1
  const int bi0   = b * NN + i0;
  const int jbase = qt * 64;
  const int isUp  = qt > (m >> 5);  // block-uniform (m>>5 == i>>6)

  const int t     = threadIdx.x;    // 0..511
  const int lane  = t & 63;
  const int hg    = t >> 6;         // wave id 0..7 -> h-slice of 32
  const int q     = lane >> 4;
  const int cc    = lane & 15;

  __shared__ __align__(16) float    xi_s[2][DD];     // 2 KB
  __shared__ __align__(16) _Float16 Af[2][16384];    // 64 KB, per-half staging
  __shared__ float pre_s[2][HH];    // S_i + b1 (both rows)      2 KB
  __shared__ float pre2_s[2][HH];   // T_i + b1 (mirror)         2 KB
  __shared__ float w2_s[HH];        // 1 KB
  __shared__ float sc_s[2][8][64];  // 4 KB

  {
    const int ii = t >> 8, u = t & 255;
    xi_s[ii][u]   = X[(size_t)(bi0 + ii) * DD + u];
    pre_s[ii][u]  = S[(size_t)(bi0 + ii) * HH + u] + b1[u];
    pre2_s[ii][u] = T[(size_t)(bi0 + ii) * HH + u] + b1[u];
    if (t < 256) w2_s[t] = W2[t];
  }

  const float* __restrict__ Tb = T + (size_t)b * NN * HH;
  const float* __restrict__ Sb = S + (size_t)b * NN * HH;

  const int jloc = t & 63;
  const int jg   = jloc >> 4;
  const int ccw  = jloc & 15;
  const float* __restrict__ xjrow = X + (size_t)(b * NN + jbase + jloc) * DD;

  // wave hg covers h = hg*32 .. hg*32+31 (hgrp pair 2hg, 2hg+1)
  const char* __restrict__ bsrc = (const char*)Wst + hg * 2048 + (size_t)lane * 16;

  floatx4 acc00[4], acc01[4], acc10[4], acc11[4];   // [i][hgrp][jg]
#pragma unroll
  for (int u = 0; u < 4; ++u) {
    acc00[u] = (floatx4)0.f; acc01[u] = (floatx4)0.f;
    acc10[u] = (floatx4)0.f; acc11[u] = (floatx4)0.f;
  }

  // B 2-deep prefetch across halves (global Wst, barrier-independent)
  half8 Bf0[2], Bf1[2];
#pragma unroll
  for (int u = 0; u < 2; ++u) {
    Bf0[u] = *(const half8*)(bsrc + (size_t)u * 16384);
    Bf1[u] = *(const half8*)(bsrc + (size_t)u * 16384 + 1024);
  }

#pragma unroll 1
  for (int half = 0; half < 2; ++half) {
    __syncthreads();                 // header ready / prior Af reads done

#pragma unroll
    for (int idx = 0; idx < 4; ++idx) {
      const int ksq = hg * 4 + idx;             // 0..31 within half (ksl = hg)
      const int d0  = (half * 32 + ksq) * 4;
      const float4 xj4 = *(const float4*)(xjrow + d0);
      const float4 xa4 = *(const float4*)&xi_s[0][d0];
      const float4 xb4 = *(const float4*)&xi_s[1][d0];
      const int off = (hg * 16 + jg * 4 + idx) * 128 + ccw * 8;
      *(half8*)&Af[0][off] = make_afrag(xa4, xj4);
      *(half8*)&Af[1][off] = make_afrag(xb4, xj4);
    }
    __syncthreads();                 // Af ready; K-loop barrier-free

#pragma unroll
    for (int ksl = 0; ksl < 8; ++ksl) {
      const int s = ksl & 1;                    // (half*8+ksl)&1, static
      const half8 Bc0 = Bf0[s], Bc1 = Bf1[s];
      {                                          // prefetch kg+2 (wrap at tail)
        const int kn = (half * 8 + ksl + 2) & 15;
        const char* bk = bsrc + (size_t)kn * 16384;
        Bf0[s] = *(const half8*)(bk);
        Bf1[s] = *(const half8*)(bk + 1024);
      }
      const _Float16* apA = &Af[0][ksl * 2048 + lane * 8];
      const _Float16* apB = &Af[1][ksl * 2048 + lane * 8];
      const half8 A00 = *(const half8*)(apA);
      const half8 A01 = *(const half8*)(apA + 512);
      const half8 A02 = *(const half8*)(apA + 1024);
      const half8 A03 = *(const half8*)(apA + 1536);
      const half8 A10 = *(const half8*)(apB);
      const half8 A11 = *(const half8*)(apB + 512);
      const half8 A12 = *(const half8*)(apB + 1024);
      const half8 A13 = *(const half8*)(apB + 1536);
      MFMA16(A00, Bc0, acc00[0]); MFMA16(A00, Bc1, acc01[0]);
      MFMA16(A01, Bc0, acc00[1]); MFMA16(A01, Bc1, acc01[1]);
      MFMA16(A02, Bc0, acc00[2]); MFMA16(A02, Bc1, acc01[2]);
      MFMA16(A03, Bc0, acc00[3]); MFMA16(A03, Bc1, acc01[3]);
      MFMA16(A10, Bc0, acc10[0]); MFMA16(A10, Bc1, acc11[0]);
      MFMA16(A11, Bc0, acc10[1]); MFMA16(A11, Bc1, acc11[1]);
      MFMA16(A12, Bc0, acc10[2]); MFMA16(A12, Bc1, acc11[2]);
      MFMA16(A13, Bc0, acc10[3]); MFMA16(A13, Bc1, acc11[3]);
    }
  }

  // ---- fused dual-i epilogue: tv loads shared across i0/i1 ----
  const int h0   = hg * 32 + cc;
  const int h1   = h0 + 16;
  const int jrow = jbase + q * 4;

#define EPILOGUE(VROW, PRE) {                                                   \
    float tv0[16], tv1[16];                                                     \
    _Pragma("unroll")                                                           \
    for (int u = 0; u < 16; ++u) {                                              \
      const size_t jb = (size_t)(jrow + (u >> 2) * 16 + (u & 3)) * HH;          \
      tv0[u] = VROW[jb + h0];                                                   \
      tv1[u] = VROW[jb + h1];                                                   \
    }                                                                           \
    const float w20 = w2_s[h0], w21 = w2_s[h1];                                 \
    const float pA0 = PRE[0][h0], pA1 = PRE[0][h1];                             \
    const float pB0 = PRE[1][h0], pB1 = PRE[1][h1];                             \
    float pI[16], pJ[16];                                                       \
    _Pragma("unroll")                                                           \
    for (int u = 0; u < 16; ++u) {                                              \
      float hv, sv;                                                             \
      hv = acc00[u >> 2][u & 3] + pA0 + tv0[u];                                 \
      sv = hv * __builtin_amdgcn_rcpf(1.f + __expf(-hv));                       \
      pI[u] = sv * w20;                                                         \
      hv = acc01[u >> 2][u & 3] + pA1 + tv1[u];                                 \
      sv = hv * __builtin_amdgcn_rcpf(1.f + __expf(-hv));                       \
      pI[u] = fmaf(sv, w21, pI[u]);                                             \
      hv = acc10[u >> 2][u & 3] + pB0 + tv0[u];                                 \
      sv = hv * __builtin_amdgcn_rcpf(1.f + __expf(-hv));                       \
      pJ[u] = sv * w20;                                                         \
      hv = acc11[u >> 2][u & 3] + pB1 + tv1[u];                                 \
      sv = hv * __builtin_amdgcn_rcpf(1.f + __expf(-hv));                       \
      pJ[u] = fmaf(sv, w21, pJ[u]);                                             \
    }                                                                           \
    _Pragma("unroll")                                                           \
    for (int u = 0; u < 16; ++u) {                                              \
      float v = pI[u];                                                          \
      v += __shfl_xor(v, 1); v += __shfl_xor(v, 2);                             \
      v += __shfl_xor(v, 4); v += __shfl_xor(v, 8);                             \
      if (cc == 0) sc_s[0][hg][(u >> 2) * 16 + q * 4 + (u & 3)] = v;            \
      float w = pJ[u];                                                          \
      w += __shfl_xor(w, 1); w += __shfl_xor(w, 2);                             \
      w += __shfl_xor(w, 4); w += __shfl_xor(w, 8);                             \
      if (cc == 0) sc_s[1][hg][(u >> 2) * 16 + q * 4 + (u & 3)] = w;            \
    } }

  // direct: H = C + (S_i+b1) + T_j
  EPILOGUE(Tb, pre_s)
  __syncthreads();

  if (t < 128) {
    const int r = t >> 6, jj = t & 63;
    float s = sc_s[r][0][jj] + sc_s[r][1][jj] + sc_s[r][2][jj] + sc_s[r][3][jj]
            + sc_s[r][4][jj] + sc_s[r][5][jj] + sc_s[r][6][jj] + sc_s[r][7][jj]
            + b2[0];
    const int jg2 = jbase + jj;
    const int ii  = i0 + r;
    if (jg2 == ii) s = NEGV;
    Sc[(size_t)(b * NN + ii) * NN + jg2] = s;
  }

  // mirror (pure-upper blocks): H' = C + S_j + (T_i+b1)
  if (isUp) {
    __syncthreads();                // sc_s reads done before overwrite
    EPILOGUE(Sb, pre2_s)
    __syncthreads();
    if (t < 128) {
      const int r = t >> 6, jj = t & 63;
      const float s = sc_s[r][0][jj] + sc_s[r][1][jj] + sc_s[r][2][jj] + sc_s[r][3][jj]
                    + sc_s[r][4][jj] + sc_s[r][5][jj] + sc_s[r][6][jj] + sc_s[r][7][jj]
                    + b2[0];
      Sc[(size_t)(b * NN + jbase + jj) * NN + (i0 + r)] = s;   // Sc[j, i]
    }
  }
#undef EPILOGUE
}

// ---------------- softmax: 1 wave per row, barrier-free ------------------------
__global__ __launch_bounds__(256) void softmax_kernel(const float* __restrict__ Sc,
                                                      float* __restrict__ out) {
  const int w    = threadIdx.x >> 6;        // wave 0..3
  const int lane = threadIdx.x & 63;
  const int bi   = blockIdx.x * 4 + w;      // row 0..1023
  const float4 v = *(const float4*)&Sc[(size_t)bi * NN + lane * 4];
  float m = fmaxf(fmaxf(v.x, v.y), fmaxf(v.z, v.w));
  m = fmaxf(m, __shfl_xor(m, 1));  m = fmaxf(m, __shfl_xor(m, 2));
  m = fmaxf(m, __shfl_xor(m, 4));  m = fmaxf(m, __shfl_xor(m, 8));
  m = fmaxf(m, __shfl_xor(m, 16)); m = fmaxf(m, __shfl_xor(m, 32));
  const float e0 = __expf(v.x - m), e1 = __expf(v.y - m);
  const float e2 = __expf(v.z - m), e3 = __expf(v.w - m);
  float sum = (e0 + e1) + (e2 + e3);
  sum += __shfl_xor(sum, 1);  sum += __shfl_xor(sum, 2);
  sum += __shfl_xor(sum, 4);  sum += __shfl_xor(sum, 8);
  sum += __shfl_xor(sum, 16); sum += __shfl_xor(sum, 32);
  const float r = 1.f / sum;
  float4 o; o.x = e0 * r; o.y = e1 * r; o.z = e2 * r; o.w = e3 * r;
  *(float4*)&out[(size_t)bi * NN + lane * 4] = o;
}

extern "C" void kernel_launch(void* const* d_in, const int* in_sizes, int n_in,
                              void* d_out, int out_size, void* d_ws, size_t ws_size,
                              hipStream_t stream) {
  const float* X  = (const float*)d_in[0];
  const float* W1 = (const float*)d_in[1];
  const float* b1 = (const float*)d_in[2];
  const float* W2 = (const float*)d_in[3];
  const float* b2 = (const float*)d_in[4];
  float* out = (float*)d_out;

  float*     Sws = (float*)d_ws;                             // 1 MB
  float*     Tws = Sws + (size_t)BB * NN * HH;               // 1 MB
  _Float16*  Wst = (_Float16*)(Tws + (size_t)BB * NN * HH);  // 256 KB
  float*     Scw = (float*)(Wst + (size_t)16 * HH * 32);     // 1 MB

  // no memset: prep writes S/T directly (no atomics, deterministic)
  prep<<<256, 256, 0, stream>>>(X, W1, Sws, Tws, Wst);
  score_mfma<<<dim3(320, BB), 512, 0, stream>>>(X, b1, W2, b2, Sws, Tws, Wst, Scw);
  softmax_kernel<<<BB * NN / 4, 256, 0, stream>>>(Scw, out);
}

// Round 6
// 162.798 us; speedup vs baseline: 1.2070x; 1.2070x over previous
//
#include <hip/hip_runtime.h>

#define BB 4
#define NN 256
#define DD 256
#define HH 256
#define NEGV -1.0e9f

typedef _Float16 half8 __attribute__((ext_vector_type(8)));
typedef __fp16   fp16x2 __attribute__((ext_vector_type(2)));
typedef float floatx4 __attribute__((ext_vector_type(4)));

// ---------------- prep: 4 rows/block, serial-K, no memset, no atomics ----------
// (R24, kept: saved ~5us of non-score time; deterministic direct stores.)
__global__ __launch_bounds__(256) void prep(const float* __restrict__ X,
                                            const float* __restrict__ W1,
                                            float* __restrict__ S,
                                            float* __restrict__ T,
                                            _Float16* __restrict__ Wst) {
  const int g = blockIdx.x;    // 0..255
  const int t = threadIdx.x;   // 0..255

  {  // weight conversion for d = g (R13 map)
    const float wcv = W1[(size_t)(2 * DD + g) * HH + t];
    const float wdv = W1[(size_t)(3 * DD + g) * HH + t];
    const int ks = g >> 4;
    const int dd = g & 15;
    const int q  = dd >> 2;
    const int e  = (dd & 3) * 2;
    const int hgrp = t >> 4;
    const int ccw  = t & 15;
    _Float16* p = Wst + ((size_t)((ks * 16 + hgrp) * 4 + q) * 16 + ccw) * 8 + e;
    p[0] = (_Float16)wcv;
    p[1] = (_Float16)wdv;
  }

  const int row0 = g * 4;
  __shared__ float xr[4][256];
  {
    const float2* src2 = (const float2*)(X + (size_t)row0 * DD);
    float2* xr2 = (float2*)xr;
    xr2[t]       = src2[t];
    xr2[t + 256] = src2[t + 256];
  }
  __syncthreads();

  const int r2 = t >> 7;       // row-pair 0..1
  const int h  = (t & 127) * 2;
  const float* __restrict__ xA = xr[r2 * 2];
  const float* __restrict__ xB = xr[r2 * 2 + 1];
  float saAx = 0.f, saAy = 0.f, sbAx = 0.f, sbAy = 0.f;
  float saBx = 0.f, saBy = 0.f, sbBx = 0.f, sbBy = 0.f;
#pragma unroll 16
  for (int d = 0; d < 256; ++d) {
    const float2 wa = *(const float2*)&W1[(size_t)d * HH + h];
    const float2 wb = *(const float2*)&W1[(size_t)(DD + d) * HH + h];
    const float a = xA[d], c = xB[d];
    saAx = fmaf(a, wa.x, saAx); saAy = fmaf(a, wa.y, saAy);
    sbAx = fmaf(a, wb.x, sbAx); sbAy = fmaf(a, wb.y, sbAy);
    saBx = fmaf(c, wa.x, saBx); saBy = fmaf(c, wa.y, saBy);
    sbBx = fmaf(c, wb.x, sbBx); sbBy = fmaf(c, wb.y, sbBy);
  }
  const int rA = row0 + r2 * 2, rB = rA + 1;
  *(float2*)&S[(size_t)rA * HH + h] = make_float2(saAx, saAy);
  *(float2*)&S[(size_t)rB * HH + h] = make_float2(saBx, saBy);
  *(float2*)&T[(size_t)rA * HH + h] = make_float2(sbAx, sbAy);
  *(float2*)&T[(size_t)rB * HH + h] = make_float2(sbBx, sbBy);
}

__device__ __forceinline__ half8 make_afrag(const float4 xi, const float4 xj) {
  fp16x2 p0 = __builtin_amdgcn_cvt_pkrtz(__builtin_fabsf(xi.x - xj.x), xi.x * xj.x);
  fp16x2 p1 = __builtin_amdgcn_cvt_pkrtz(__builtin_fabsf(xi.y - xj.y), xi.y * xj.y);
  fp16x2 p2 = __builtin_amdgcn_cvt_pkrtz(__builtin_fabsf(xi.z - xj.z), xi.z * xj.z);
  fp16x2 p3 = __builtin_amdgcn_cvt_pkrtz(__builtin_fabsf(xi.w - xj.w), xi.w * xj.w);
  uint4 u;
  u.x = __builtin_bit_cast(unsigned int, p0);
  u.y = __builtin_bit_cast(unsigned int, p1);
  u.z = __builtin_bit_cast(unsigned int, p2);
  u.w = __builtin_bit_cast(unsigned int, p3);
  return __builtin_bit_cast(half8, u);
}

#define MFMA16(af, bf, acc) acc = __builtin_amdgcn_mfma_f32_16x16x32_f16(af, bf, acc, 0, 0, 0)

// ---------------- score: R23 structure + qt-major order + 4-deep B prefetch ----
// R25 theory: per-XCD hot set (Wst 256K + X 1M + S 1M + T 1M + Sc stream) ~4.3MB
// > 4MB L2/XCD -> K-loop B loads + epilogue row loads served at L3 (~2x L2
// latency); invariant across R0-R24 restructures, explaining the pinned 100us.
// Fix 1: qt-major block enumeration (same 640 (i,qt) pairs) -> in-flight window
// shares one T/S j-slice (64KB hot vs 1MB) + clustered mirror writes.
// Fix 2: B prefetch depth 2->4 (+16 VGPR, ~112 total <= 128, 2 blocks/CU kept).
// Score math bit-identical -> absmax must stay 3.051758e-05.
// Falsifier: score 100us +-5% -> locality theory dead (then: 32x32 MFMA or limit).
__global__ __launch_bounds__(512, 4) void score_mfma(
    const float* __restrict__ X,  const float* __restrict__ b1,
    const float* __restrict__ W2, const float* __restrict__ b2,
    const float* __restrict__ S,  const float* __restrict__ T,
    const _Float16* __restrict__ Wst, float* __restrict__ Sc) {

  const int beta = blockIdx.x;      // 0..639, qt-major
  const int b    = blockIdx.y;
  int i, qt;
  if (beta < 64)       { qt = 0; i = beta; }           // i 0..63
  else if (beta < 192) { qt = 1; i = beta - 64; }      // i 0..127
  else if (beta < 384) { qt = 2; i = beta - 192; }     // i 0..191
  else                 { qt = 3; i = beta - 384; }     // i 0..255
  const int bi    = b * NN + i;
  const int jbase = qt * 64;
  const int isUp  = qt > (i >> 6);  // block-uniform

  const int t     = threadIdx.x;    // 0..511
  const int lane  = t & 63;
  const int hg    = t >> 6;         // wave id 0..7 -> h-slice of 32
  const int q     = lane >> 4;
  const int cc    = lane & 15;

  __shared__ __align__(16) float    xi_s[DD];
  __shared__ __align__(16) _Float16 Af[32768];   // 64 KB: [kg 0..15][jg][qw][ccw][e]
  __shared__ float pre_s[HH];       // S_i + b1
  __shared__ float pre2_s[HH];      // T_i + b1 (mirror)
  __shared__ float w2_s[HH];
  __shared__ float sc_s[8][64];

  if (t < 256) {
    xi_s[t]  = X[(size_t)bi * DD + t];
    pre_s[t] = S[(size_t)bi * HH + t] + b1[t];
  } else {
    const int u = t - 256;
    pre2_s[u] = T[(size_t)bi * HH + u] + b1[u];
    w2_s[u]   = W2[u];
  }

  const float* __restrict__ Tb = T + (size_t)b * NN * HH;
  const float* __restrict__ Sb = S + (size_t)b * NN * HH;

  const int jloc = t & 63;
  const int jg   = jloc >> 4;
  const int ccw  = jloc & 15;
  const float* __restrict__ xjrow = X + (size_t)(b * NN + jbase + jloc) * DD;

  // wave hg covers hgrp pair 2hg..2hg+1 (h = hg*32 .. hg*32+31)
  const char* __restrict__ bsrc = (const char*)Wst + hg * 2048 + (size_t)lane * 16;

  // B prefetch, 4-deep (global Wst, barrier-independent) — issue before staging
  half8 Bf0[4], Bf1[4];
#pragma unroll
  for (int u = 0; u < 4; ++u) {
    Bf0[u] = *(const half8*)(bsrc + (size_t)u * 16384);
    Bf1[u] = *(const half8*)(bsrc + (size_t)u * 16384 + 1024);
  }

  __syncthreads();                  // header (xi_s) ready

  // ---- stage full K (both halves) in one pass: 8 frags/thread ----
  {
    const int sgrp = t >> 6;
#pragma unroll
    for (int idx = 0; idx < 8; ++idx) {
      const int ksqg = sgrp * 8 + idx;          // 0..63 k-quads
      const int d0   = ksqg * 4;
      const int kg   = ksqg >> 2;               // 0..15
      const int qw   = ksqg & 3;
      const float4 xi4 = *(const float4*)&xi_s[d0];
      const float4 xj4 = *(const float4*)(xjrow + d0);
      *(half8*)&Af[kg * 2048 + (jg * 4 + qw) * 128 + ccw * 8] = make_afrag(xi4, xj4);
    }
  }
  __syncthreads();                  // Af ready; K-loop barrier-free, 16 steps

  floatx4 acc0[4], acc1[4];         // [jj] for the wave's 2 h-16 groups
#pragma unroll
  for (int u = 0; u < 4; ++u) { acc0[u] = (floatx4)0.f; acc1[u] = (floatx4)0.f; }

  const _Float16* ap0 = &Af[lane * 8];
  half8 An0 = *(const half8*)(ap0);
  half8 An1 = *(const half8*)(ap0 + 512);
  half8 An2 = *(const half8*)(ap0 + 1024);
  half8 An3 = *(const half8*)(ap0 + 1536);

#pragma unroll
  for (int kg = 0; kg < 16; ++kg) {
    const int s = kg & 3;                       // static under full unroll
    const half8 Bc0 = Bf0[s], Bc1 = Bf1[s];
    const half8 Ac0 = An0, Ac1 = An1, Ac2 = An2, Ac3 = An3;
    if (kg < 12) {
      const char* bk = bsrc + (size_t)(kg + 4) * 16384;
      Bf0[s] = *(const half8*)(bk);
      Bf1[s] = *(const half8*)(bk + 1024);
    }
    if (kg < 15) {
      const _Float16* ap = &Af[(kg + 1) * 2048 + lane * 8];
      An0 = *(const half8*)(ap);
      An1 = *(const half8*)(ap + 512);
      An2 = *(const half8*)(ap + 1024);
      An3 = *(const half8*)(ap + 1536);
    }
    MFMA16(Ac0, Bc0, acc0[0]); MFMA16(Ac0, Bc1, acc1[0]);
    MFMA16(Ac1, Bc0, acc0[1]); MFMA16(Ac1, Bc1, acc1[1]);
    MFMA16(Ac2, Bc0, acc0[2]); MFMA16(Ac2, Bc1, acc1[2]);
    MFMA16(Ac3, Bc0, acc0[3]); MFMA16(Ac3, Bc1, acc1[3]);
  }

  // ---- epilogues: loads hoisted 32-deep, then silu+dot, then wave-reduce ----
  const int h0   = hg * 32 + cc;
  const int h1   = h0 + 16;
  const int jrow = jbase + q * 4;

#define EPILOGUE(VROW, PRE) {                                                   \
    float tv0[16], tv1[16];                                                     \
    _Pragma("unroll")                                                           \
    for (int u = 0; u < 16; ++u) {                                              \
      const size_t j = (size_t)(jrow + (u >> 2) * 16 + (u & 3)) * HH;           \
      tv0[u] = VROW[j + h0];                                                    \
      tv1[u] = VROW[j + h1];                                                    \
    }                                                                           \
    const float w20 = w2_s[h0], pv0 = PRE[h0];                                  \
    const float w21 = w2_s[h1], pv1 = PRE[h1];                                  \
    float p[16];                                                                \
    _Pragma("unroll")                                                           \
    for (int u = 0; u < 16; ++u) {                                              \
      const float hv0 = acc0[u >> 2][u & 3] + pv0 + tv0[u];                     \
      const float sv0 = hv0 * __builtin_amdgcn_rcpf(1.f + __expf(-hv0));        \
      p[u] = sv0 * w20;                                                         \
      const float hv1 = acc1[u >> 2][u & 3] + pv1 + tv1[u];                     \
      const float sv1 = hv1 * __builtin_amdgcn_rcpf(1.f + __expf(-hv1));        \
      p[u] = fmaf(sv1, w21, p[u]);                                              \
    }                                                                           \
    _Pragma("unroll")                                                           \
    for (int u = 0; u < 16; ++u) {                                              \
      float v = p[u];                                                           \
      v += __shfl_xor(v, 1); v += __shfl_xor(v, 2);                             \
      v += __shfl_xor(v, 4); v += __shfl_xor(v, 8);                             \
      if (cc == 0) sc_s[hg][(u >> 2) * 16 + q * 4 + (u & 3)] = v;               \
    } }

  // direct: H = C + (S_i+b1) + T_j
  EPILOGUE(Tb, pre_s)
  __syncthreads();

  if (t < 64) {
    float s = sc_s[0][t] + sc_s[1][t] + sc_s[2][t] + sc_s[3][t]
            + sc_s[4][t] + sc_s[5][t] + sc_s[6][t] + sc_s[7][t] + b2[0];
    const int jg2 = jbase + t;
    if (jg2 == i) s = NEGV;
    Sc[(size_t)bi * NN + jg2] = s;
  }

  // mirror (pure-upper blocks): H' = C + S_j + (T_i+b1)
  if (isUp) {
    __syncthreads();                // sc_s reads done before overwrite
    EPILOGUE(Sb, pre2_s)
    __syncthreads();
    if (t < 64) {
      const float s = sc_s[0][t] + sc_s[1][t] + sc_s[2][t] + sc_s[3][t]
                    + sc_s[4][t] + sc_s[5][t] + sc_s[6][t] + sc_s[7][t] + b2[0];
      Sc[(size_t)(b * NN + jbase + t) * NN + i] = s;   // Sc[j, i]
    }
  }
#undef EPILOGUE
}

// ---------------- softmax: 1 wave per row, barrier-free ------------------------
__global__ __launch_bounds__(256) void softmax_kernel(const float* __restrict__ Sc,
                                                      float* __restrict__ out) {
  const int w    = threadIdx.x >> 6;        // wave 0..3
  const int lane = threadIdx.x & 63;
  const int bi   = blockIdx.x * 4 + w;      // row 0..1023
  const float4 v = *(const float4*)&Sc[(size_t)bi * NN + lane * 4];
  float m = fmaxf(fmaxf(v.x, v.y), fmaxf(v.z, v.w));
  m = fmaxf(m, __shfl_xor(m, 1));  m = fmaxf(m, __shfl_xor(m, 2));
  m = fmaxf(m, __shfl_xor(m, 4));  m = fmaxf(m, __shfl_xor(m, 8));
  m = fmaxf(m, __shfl_xor(m, 16)); m = fmaxf(m, __shfl_xor(m, 32));
  const float e0 = __expf(v.x - m), e1 = __expf(v.y - m);
  const float e2 = __expf(v.z - m), e3 = __expf(v.w - m);
  float sum = (e0 + e1) + (e2 + e3);
  sum += __shfl_xor(sum, 1);  sum += __shfl_xor(sum, 2);
  sum += __shfl_xor(sum, 4);  sum += __shfl_xor(sum, 8);
  sum += __shfl_xor(sum, 16); sum += __shfl_xor(sum, 32);
  const float r = 1.f / sum;
  float4 o; o.x = e0 * r; o.y = e1 * r; o.z = e2 * r; o.w = e3 * r;
  *(float4*)&out[(size_t)bi * NN + lane * 4] = o;
}

extern "C" void kernel_launch(void* const* d_in, const int* in_sizes, int n_in,
                              void* d_out, int out_size, void* d_ws, size_t ws_size,
                              hipStream_t stream) {
  const float* X  = (const float*)d_in[0];
  const float* W1 = (const float*)d_in[1];
  const float* b1 = (const float*)d_in[2];
  const float* W2 = (const float*)d_in[3];
  const float* b2 = (const float*)d_in[4];
  float* out = (float*)d_out;

  float*     Sws = (float*)d_ws;                             // 1 MB
  float*     Tws = Sws + (size_t)BB * NN * HH;               // 1 MB
  _Float16*  Wst = (_Float16*)(Tws + (size_t)BB * NN * HH);  // 256 KB
  float*     Scw = (float*)(Wst + (size_t)16 * HH * 32);     // 1 MB

  // no memset: prep writes S/T directly (no atomics, deterministic)
  prep<<<256, 256, 0, stream>>>(X, W1, Sws, Tws, Wst);
  score_mfma<<<dim3(640, BB), 512, 0, stream>>>(X, b1, W2, b2, Sws, Tws, Wst, Scw);
  softmax_kernel<<<BB * NN / 4, 256, 0, stream>>>(Scw, out);
}